// Round 3
// baseline (618.526 us; speedup 1.0000x reference)
//
#include <hip/hip_runtime.h>
#include <hip/hip_bf16.h>
#include <cmath>
#include <cstdint>

typedef __attribute__((ext_vector_type(8))) short short8;
typedef __attribute__((ext_vector_type(4))) float floatx4;
typedef __attribute__((ext_vector_type(4))) unsigned int uintx4;

typedef const __attribute__((address_space(1))) unsigned int* gas_p;
typedef __attribute__((address_space(3))) unsigned int* las_p;

#define LOG2E 1.4426950408889634f

__device__ inline unsigned short f2bf(float f) {
  unsigned int u = __builtin_bit_cast(unsigned int, f);
  unsigned int r = (u + 0x7FFFu + ((u >> 16) & 1u)) >> 16;
  return (unsigned short)r;
}
__device__ inline float bf2f(unsigned short h) {
  unsigned int u = ((unsigned int)h) << 16;
  return __builtin_bit_cast(float, u);
}

// ---------------- elementwise fp32 -> bf16 (float4 loads) ----------------
__global__ void k_f32_to_bf16(const float* __restrict__ in, unsigned short* __restrict__ out, int n4) {
  int i = blockIdx.x * 256 + threadIdx.x;
  if (i >= n4) return;
  float4 v = reinterpret_cast<const float4*>(in)[i];
  uint2 o;
  o.x = (unsigned)f2bf(v.x) | ((unsigned)f2bf(v.y) << 16);
  o.y = (unsigned)f2bf(v.z) | ((unsigned)f2bf(v.w) << 16);
  reinterpret_cast<uint2*>(out)[i] = o;
}

// ---------------- transpose + convert + scale: fp32 [K][N] -> bf16 [N][K] ----------------
__global__ void k_transpose_w(const float* __restrict__ in, unsigned short* __restrict__ out,
                              int K, int N, float scl) {
  __shared__ float t[32][33];
  int n0 = blockIdx.x * 32, k0 = blockIdx.y * 32;
  int tx = threadIdx.x & 31, ty = threadIdx.x >> 5; // 256 threads: ty 0..7
  #pragma unroll
  for (int r = ty; r < 32; r += 8)
    t[r][tx] = in[(long)(k0 + r) * N + n0 + tx];
  __syncthreads();
  #pragma unroll
  for (int r = ty; r < 32; r += 8)
    out[(long)(n0 + r) * K + k0 + tx] = f2bf(t[tx][r] * scl);
}

// ---------------- small fp32 GEMM: out[d][0..3] = W[d,:] @ Ws (Kw x 4) ----------------
__global__ void k_wproj(const float* __restrict__ W, const float* __restrict__ Ws,
                        float* __restrict__ out, int Kw) {
  int d = blockIdx.x;
  float a0 = 0, a1 = 0, a2 = 0, a3 = 0;
  for (int j = threadIdx.x; j < Kw; j += 256) {
    float w = W[(long)d * Kw + j];
    float4 g = reinterpret_cast<const float4*>(Ws)[j];
    a0 += w * g.x; a1 += w * g.y; a2 += w * g.z; a3 += w * g.w;
  }
  #pragma unroll
  for (int off = 1; off < 64; off <<= 1) {
    a0 += __shfl_xor(a0, off, 64); a1 += __shfl_xor(a1, off, 64);
    a2 += __shfl_xor(a2, off, 64); a3 += __shfl_xor(a3, off, 64);
  }
  __shared__ float red[4][4];
  if ((threadIdx.x & 63) == 0) {
    int wv = threadIdx.x >> 6;
    red[wv][0] = a0; red[wv][1] = a1; red[wv][2] = a2; red[wv][3] = a3;
  }
  __syncthreads();
  if (threadIdx.x < 4) {
    int nn = threadIdx.x;
    out[d * 4 + nn] = red[0][nn] + red[1][nn] + red[2][nn] + red[3][nn];
  }
}

// ---------------- bias (fp32), pre-masked + log2e-scaled ----------------
// stores: v>0 ? v*log2e : -INF   (v = sigmoid(gate)*delta, fp32-exact sign)
__global__ void k_bias(const float* __restrict__ hs, const float* __restrict__ Wqg,
                       const float* __restrict__ Wvd, float* __restrict__ bias) {
  int row = blockIdx.x;           // b*2048 + s
  int b = row >> 11, s = row & 2047;
  float g0 = 0, g1 = 0, g2 = 0, g3 = 0, d0 = 0, d1 = 0, d2 = 0, d3 = 0;
  const float* h = hs + (long)row * 2048;
  for (int j = threadIdx.x; j < 2048; j += 256) {
    float x = h[j];
    float4 a = reinterpret_cast<const float4*>(Wqg)[j];
    float4 c = reinterpret_cast<const float4*>(Wvd)[j];
    g0 += x * a.x; g1 += x * a.y; g2 += x * a.z; g3 += x * a.w;
    d0 += x * c.x; d1 += x * c.y; d2 += x * c.z; d3 += x * c.w;
  }
  #pragma unroll
  for (int off = 1; off < 64; off <<= 1) {
    g0 += __shfl_xor(g0, off, 64); g1 += __shfl_xor(g1, off, 64);
    g2 += __shfl_xor(g2, off, 64); g3 += __shfl_xor(g3, off, 64);
    d0 += __shfl_xor(d0, off, 64); d1 += __shfl_xor(d1, off, 64);
    d2 += __shfl_xor(d2, off, 64); d3 += __shfl_xor(d3, off, 64);
  }
  __shared__ float red[4][8];
  if ((threadIdx.x & 63) == 0) {
    int wv = threadIdx.x >> 6;
    red[wv][0] = g0; red[wv][1] = g1; red[wv][2] = g2; red[wv][3] = g3;
    red[wv][4] = d0; red[wv][5] = d1; red[wv][6] = d2; red[wv][7] = d3;
  }
  __syncthreads();
  if (threadIdx.x < 4) {
    int nn = threadIdx.x;
    float gg = red[0][nn] + red[1][nn] + red[2][nn] + red[3][nn];
    float dd = red[0][4 + nn] + red[1][4 + nn] + red[2][4 + nn] + red[3][4 + nn];
    float sig = 1.0f / (1.0f + __expf(-gg));
    float v = sig * dd;
    bias[(b * 4 + nn) * 2048 + s] = (v > 0.0f) ? v * LOG2E : -INFINITY;
  }
}

// ---------------- bf16 MFMA GEMM: C[M,N] = A[M,K] @ Bt[N,K]^T ----------------
// m97 structure: 128x128 tile, BK=32, async global_load_lds width=16.
template <int WRITE_BF16>
__global__ __launch_bounds__(256, 2) void k_gemm_bt(
    const unsigned short* __restrict__ A, const unsigned short* __restrict__ Bt,
    void* __restrict__ Cout, int M, int N, int K) {
  __shared__ __align__(16) unsigned short As[128 * 32];
  __shared__ __align__(16) unsigned short Bs[128 * 32];
  const int tid = threadIdx.x;
  const int lane = tid & 63, wave = tid >> 6;
  const int quad = lane >> 4, l16 = lane & 15;
  const long bm = (long)blockIdx.y * 128, bn = (long)blockIdx.x * 128;
  const int wm = (wave >> 1) * 64, wn = (wave & 1) * 64;

  const floatx4 fz = {0.f, 0.f, 0.f, 0.f};
  floatx4 acc[4][4];
  #pragma unroll
  for (int i = 0; i < 4; i++)
    #pragma unroll
    for (int j = 0; j < 4; j++) acc[i][j] = fz;

  const int r0 = tid >> 2, c0 = (tid & 3) * 8;
  const unsigned short* Ag = A + (bm + r0) * K + c0;
  const unsigned short* Bg = Bt + (bn + r0) * K + c0;
  unsigned short* AsW0 = As + (wave * 16) * 32;
  unsigned short* AsW1 = As + (wave * 16 + 64) * 32;
  unsigned short* BsW0 = Bs + (wave * 16) * 32;
  unsigned short* BsW1 = Bs + (wave * 16 + 64) * 32;

  for (int kt = 0; kt < K; kt += 32) {
    __syncthreads();
    __builtin_amdgcn_global_load_lds((gas_p)(const void*)(Ag + kt),
                                     (las_p)(void*)AsW0, 16, 0, 0);
    __builtin_amdgcn_global_load_lds((gas_p)(const void*)(Ag + (long)64 * K + kt),
                                     (las_p)(void*)AsW1, 16, 0, 0);
    __builtin_amdgcn_global_load_lds((gas_p)(const void*)(Bg + kt),
                                     (las_p)(void*)BsW0, 16, 0, 0);
    __builtin_amdgcn_global_load_lds((gas_p)(const void*)(Bg + (long)64 * K + kt),
                                     (las_p)(void*)BsW1, 16, 0, 0);
    __syncthreads();
    short8 af[4], bf[4];
    #pragma unroll
    for (int i = 0; i < 4; i++)
      af[i] = *reinterpret_cast<const short8*>(&As[(wm + i * 16 + l16) * 32 + quad * 8]);
    #pragma unroll
    for (int j = 0; j < 4; j++)
      bf[j] = *reinterpret_cast<const short8*>(&Bs[(wn + j * 16 + l16) * 32 + quad * 8]);
    #pragma unroll
    for (int i = 0; i < 4; i++)
      #pragma unroll
      for (int j = 0; j < 4; j++)
        acc[i][j] = __builtin_amdgcn_mfma_f32_16x16x32_bf16(af[i], bf[j], acc[i][j], 0, 0, 0);
  }
  #pragma unroll
  for (int i = 0; i < 4; i++)
    #pragma unroll
    for (int j = 0; j < 4; j++)
      #pragma unroll
      for (int r = 0; r < 4; r++) {
        const long row = bm + wm + i * 16 + quad * 4 + r;
        const long col = bn + wn + j * 16 + l16;
        const float v = acc[i][j][r];
        if (WRITE_BF16)
          ((unsigned short*)Cout)[row * N + col] = f2bf(v);
        else
          ((float*)Cout)[row * N + col] = v;
      }
}

// ---------------- bf16 transpose of V slice: qkv[.,2560+c] -> vT[(b*512+c)*2048+s] ----------------
__global__ void k_transpose_v(const unsigned short* __restrict__ qkv, unsigned short* __restrict__ vt) {
  __shared__ unsigned short t[32][33];
  int c0 = blockIdx.x * 32, s0 = blockIdx.y * 32, b = blockIdx.z;
  int tx = threadIdx.x & 31, ty = threadIdx.x >> 5;
  #pragma unroll
  for (int r = ty; r < 32; r += 8)
    t[r][tx] = qkv[((long)(b * 2048 + s0 + r)) * 3072 + 2560 + c0 + tx];
  __syncthreads();
  #pragma unroll
  for (int r = ty; r < 32; r += 8)
    vt[((long)(b * 512 + c0 + r)) * 2048 + s0 + tx] = t[tx][r];
}

// ---------------- vmean from vT rows (coalesced) ----------------
__global__ void k_vmean2(const unsigned short* __restrict__ vT, float* __restrict__ vmean) {
  const int row = blockIdx.x;  // 1024
  const int tid = threadIdx.x, lane = tid & 63, wave = tid >> 6;
  uintx4 v = reinterpret_cast<const uintx4*>(vT + (long)row * 2048)[tid];
  float s = 0.f;
  #pragma unroll
  for (int i = 0; i < 4; i++) {
    unsigned u = v[i];
    s += bf2f((unsigned short)(u & 0xffff)) + bf2f((unsigned short)(u >> 16));
  }
  #pragma unroll
  for (int off = 1; off < 64; off <<= 1) s += __shfl_xor(s, off, 64);
  __shared__ float red[4];
  if (lane == 0) red[wave] = s;
  __syncthreads();
  if (tid == 0) vmean[row] = (red[0] + red[1] + red[2] + red[3]) * (1.0f / 2048.0f);
}

// ---------------- online-softmax tile update (FULL = no causal check needed) ----------------
template <bool FULL>
__device__ __forceinline__ void softmax_tile(
    floatx4 (&sacc)[2][4], floatx4 (&oacc)[2][8],
    float (&mrow)[2][4], float (&lrow)[2][4],
    const float (&bcol)[4], int q0, int k0, int quad, int l16) {
  #pragma unroll
  for (int mt = 0; mt < 2; mt++) {
    #pragma unroll
    for (int r = 0; r < 4; r++) {
      const int qrow = q0 + mt * 16 + quad * 4 + r;
      float mx = -INFINITY;
      #pragma unroll
      for (int nt = 0; nt < 4; nt++) {
        float x = sacc[mt][nt][r] + bcol[nt];  // bcol pre-masked (-INF) + log2e-scaled
        if (!FULL) {
          const int key = k0 + nt * 16 + l16;
          x = (key <= qrow) ? x : -INFINITY;
        }
        sacc[mt][nt][r] = x;
        mx = fmaxf(mx, x);
      }
      mx = fmaxf(mx, __shfl_xor(mx, 1, 64));
      mx = fmaxf(mx, __shfl_xor(mx, 2, 64));
      mx = fmaxf(mx, __shfl_xor(mx, 4, 64));
      mx = fmaxf(mx, __shfl_xor(mx, 8, 64));
      const float mn = fmaxf(mrow[mt][r], mx);
      const float mnc = fmaxf(mn, -1e38f);     // clamp: fully-masked rows -> exp2 gives 0, no NaN
      const float alpha = __builtin_amdgcn_exp2f(mrow[mt][r] - mnc);
      float rs = 0.0f;
      #pragma unroll
      for (int nt = 0; nt < 4; nt++) {
        float p = __builtin_amdgcn_exp2f(sacc[mt][nt][r] - mnc);
        sacc[mt][nt][r] = p;
        rs += p;
      }
      rs += __shfl_xor(rs, 1, 64);
      rs += __shfl_xor(rs, 2, 64);
      rs += __shfl_xor(rs, 4, 64);
      rs += __shfl_xor(rs, 8, 64);
      mrow[mt][r] = mn;
      lrow[mt][r] = lrow[mt][r] * alpha + rs;
      #pragma unroll
      for (int j = 0; j < 8; j++) oacc[mt][j][r] *= alpha;
    }
  }
}

// ---------------- flash attention with dynamic mask ----------------
// grid 512 = qt(16, reversed/LPT) x b(2) x n(4) x g(4); 4 waves; wave owns 32 q rows
// LDS: Ks(64x144) overlaid by per-wave Ps(4 x 32x72) + Vs(128x72) = 36,864 B -> 3 blocks/CU
__global__ __launch_bounds__(256, 3) void k_attn(
    const unsigned short* __restrict__ qkv,  // [4096][3072] (q | k | v); q pre-scaled by scale*log2e
    const float* __restrict__ biasb,         // [8][2048] pre-masked, log2e-scaled
    const unsigned short* __restrict__ vT,   // [1024][2048]
    const float* __restrict__ vmean,         // [1024]
    unsigned short* __restrict__ o)          // [4096][2048]
{
  int idx = blockIdx.x;
  const int g = idx & 3;
  const int n = (idx >> 2) & 3;
  const int b = (idx >> 4) & 1;
  const int qt = 15 - (idx >> 5);            // big blocks first (LPT)
  const int tid = threadIdx.x, lane = tid & 63, wave = tid >> 6;
  const int quad = lane >> 4, l16 = lane & 15;
  const int q0 = qt * 128 + wave * 32;

  __shared__ __align__(16) unsigned short KPs[64 * 144]; // K tile; overlaid by P after barrier(3)
  __shared__ __align__(16) unsigned short Vs[128 * 72];  // [hd][key]
  unsigned short* Psw = KPs + wave * 2304;               // 32 x 72, per-wave private

  // Q fragments (A-operand): row = q0+mt*16+l16, k = ks*32+quad*8..+8
  short8 qf[2][4];
  {
    const unsigned short* qp = qkv + (long)(b * 2048) * 3072 + (n * 4 + g) * 128;
    #pragma unroll
    for (int mt = 0; mt < 2; mt++)
      #pragma unroll
      for (int ks = 0; ks < 4; ks++)
        qf[mt][ks] = *reinterpret_cast<const short8*>(
            qp + (long)(q0 + mt * 16 + l16) * 3072 + ks * 32 + quad * 8);
  }

  const floatx4 fz = {0.f, 0.f, 0.f, 0.f};
  floatx4 oacc[2][8];
  #pragma unroll
  for (int mt = 0; mt < 2; mt++)
    #pragma unroll
    for (int j = 0; j < 8; j++) oacc[mt][j] = fz;
  float mrow[2][4], lrow[2][4];
  #pragma unroll
  for (int mt = 0; mt < 2; mt++)
    #pragma unroll
    for (int r = 0; r < 4; r++) { mrow[mt][r] = -INFINITY; lrow[mt][r] = 0.0f; }

  const float* biasrow = biasb + (b * 4 + n) * 2048;
  const int kend = qt * 128 + 128;
  for (int k0 = 0; k0 < kend; k0 += 64) {
    __syncthreads();  // (1) prev-iter P/V LDS reads complete
    {
      const unsigned short* kp = qkv + (long)(b * 2048 + k0) * 3072 + 2048 + n * 128;
      #pragma unroll
      for (int it = 0; it < 4; it++) {
        int seg = tid + it * 256;
        int kk = seg >> 4, hdo = (seg & 15) * 8;
        *reinterpret_cast<uintx4*>(&KPs[kk * 144 + hdo]) =
            *reinterpret_cast<const uintx4*>(kp + (long)kk * 3072 + hdo);
      }
      const unsigned short* vp = vT + (long)(b * 512 + n * 128) * 2048 + k0;
      #pragma unroll
      for (int it = 0; it < 4; it++) {
        int seg = tid + it * 256;
        int hd = seg >> 3, ko = (seg & 7) * 8;
        *reinterpret_cast<uintx4*>(&Vs[hd * 72 + ko]) =
            *reinterpret_cast<const uintx4*>(vp + (long)hd * 2048 + ko);
      }
    }
    __syncthreads();  // (2) staging visible

    const bool active = (k0 <= q0 + 31);  // any key of this tile usable by this wave?
    floatx4 sacc[2][4];
    float bcol[4];
    if (active) {
      #pragma unroll
      for (int nt = 0; nt < 4; nt++) bcol[nt] = biasrow[k0 + nt * 16 + l16];
      #pragma unroll
      for (int mt = 0; mt < 2; mt++)
        #pragma unroll
        for (int nt = 0; nt < 4; nt++) sacc[mt][nt] = fz;
      #pragma unroll
      for (int ks = 0; ks < 4; ks++) {
        short8 kf[4];
        #pragma unroll
        for (int nt = 0; nt < 4; nt++)
          kf[nt] = *reinterpret_cast<const short8*>(&KPs[(nt * 16 + l16) * 144 + ks * 32 + quad * 8]);
        #pragma unroll
        for (int mt = 0; mt < 2; mt++)
          #pragma unroll
          for (int nt = 0; nt < 4; nt++)
            sacc[mt][nt] = __builtin_amdgcn_mfma_f32_16x16x32_bf16(qf[mt][ks], kf[nt], sacc[mt][nt], 0, 0, 0);
      }
    }
    __syncthreads();  // (3) ALL waves done reading K tile; P may now overlay it

    if (active) {
      const bool full = (k0 + 63 <= q0);  // tile entirely below diagonal for this wave
      if (full)
        softmax_tile<true>(sacc, oacc, mrow, lrow, bcol, q0, k0, quad, l16);
      else
        softmax_tile<false>(sacc, oacc, mrow, lrow, bcol, q0, k0, quad, l16);

      // P (C-layout) -> per-wave LDS -> A-layout; no barrier needed (wave-private)
      #pragma unroll
      for (int mt = 0; mt < 2; mt++)
        #pragma unroll
        for (int nt = 0; nt < 4; nt++)
          #pragma unroll
          for (int r = 0; r < 4; r++)
            Psw[(mt * 16 + quad * 4 + r) * 72 + nt * 16 + l16] = f2bf(sacc[mt][nt][r]);

      // O += P @ V
      #pragma unroll
      for (int ks2 = 0; ks2 < 2; ks2++) {
        short8 pf[2];
        #pragma unroll
        for (int mt = 0; mt < 2; mt++)
          pf[mt] = *reinterpret_cast<const short8*>(&Psw[(mt * 16 + l16) * 72 + ks2 * 32 + quad * 8]);
        #pragma unroll
        for (int j = 0; j < 8; j++) {
          short8 vf = *reinterpret_cast<const short8*>(&Vs[(j * 16 + l16) * 72 + ks2 * 32 + quad * 8]);
          #pragma unroll
          for (int mt = 0; mt < 2; mt++)
            oacc[mt][j] = __builtin_amdgcn_mfma_f32_16x16x32_bf16(pf[mt], vf, oacc[mt][j], 0, 0, 0);
        }
      }
    }
  }

  // epilogue
  const long obase = (long)(b * 2048) * 2048 + (n * 4 + g) * 128;
  #pragma unroll
  for (int mt = 0; mt < 2; mt++)
    #pragma unroll
    for (int r = 0; r < 4; r++) {
      const int qrow = q0 + mt * 16 + quad * 4 + r;
      const float l = lrow[mt][r];
      const float inv = (l > 0.0f) ? 1.0f / l : 0.0f;
      #pragma unroll
      for (int j = 0; j < 8; j++) {
        const int hd = j * 16 + l16;
        float v = oacc[mt][j][r] * inv;
        if (l <= 0.0f) v = vmean[(b * 4 + n) * 128 + hd];  // empty row: uniform softmax over ALL keys
        o[obase + (long)qrow * 2048 + hd] = f2bf(v);
      }
    }
}

extern "C" void kernel_launch(void* const* d_in, const int* in_sizes, int n_in,
                              void* d_out, int out_size, void* d_ws, size_t ws_size,
                              hipStream_t stream) {
  const float* hs = (const float*)d_in[0];
  const float* Wq = (const float*)d_in[1];
  const float* Wk = (const float*)d_in[2];
  const float* Wv = (const float*)d_in[3];
  const float* Wg = (const float*)d_in[4];
  const float* Wd = (const float*)d_in[5];
  const float* Wo = (const float*)d_in[6];
  float* out = (float*)d_out;

  char* ws = (char*)d_ws;
  unsigned short* hsb   = (unsigned short*)(ws);               // 16,777,216 B
  unsigned short* Wcomb = (unsigned short*)(ws + 16777216);    // 12,582,912 B  [3072][2048]
  unsigned short* Wot   = (unsigned short*)(ws + 29360128);    //  8,388,608 B
  float*  Wqg   = (float*)(ws + 37748736);                     //     32,768 B
  float*  Wvd   = (float*)(ws + 37781504);                     //     32,768 B
  float*  biasb = (float*)(ws + 37814272);                     //     65,536 B
  unsigned short* qkv = (unsigned short*)(ws + 37879808);      // 25,165,824 B  [4096][3072]
  unsigned short* vT  = (unsigned short*)(ws + 63045632);      //  4,194,304 B
  float*  vmean = (float*)(ws + 67239936);                     //      4,096 B
  unsigned short* ob  = (unsigned short*)(ws + 67244032);      // 16,777,216 B

  const float QSCALE = 0.08838834764831845f * LOG2E;  // fold softmax scale + log2e into Q

  // 1. hs -> bf16
  k_f32_to_bf16<<<2097152 / 256, 256, 0, stream>>>(hs, hsb, 2097152);

  // 2. weight transposes (fp32 -> bf16, B^T layout); Wq pre-scaled
  {
    dim3 g1(2048 / 32, 2048 / 32);
    dim3 g2(512 / 32, 2048 / 32);
    k_transpose_w<<<g1, 256, 0, stream>>>(Wq, Wcomb, 2048, 2048, QSCALE);
    k_transpose_w<<<g2, 256, 0, stream>>>(Wk, Wcomb + (long)2048 * 2048, 2048, 512, 1.0f);
    k_transpose_w<<<g2, 256, 0, stream>>>(Wv, Wcomb + (long)2560 * 2048, 2048, 512, 1.0f);
    k_transpose_w<<<g1, 256, 0, stream>>>(Wo, Wot, 2048, 2048, 1.0f);
  }

  // 3. fused weight products for fp32 gate/delta path
  k_wproj<<<2048, 256, 0, stream>>>(Wq, Wg, Wqg, 2048);
  k_wproj<<<2048, 256, 0, stream>>>(Wv, Wd, Wvd, 512);

  // 4. bias (fp32): pre-masked + log2e-scaled
  k_bias<<<4096, 256, 0, stream>>>(hs, Wqg, Wvd, biasb);

  // 5. fused QKV projection GEMM
  {
    dim3 gq(3072 / 128, 4096 / 128);
    k_gemm_bt<1><<<gq, 256, 0, stream>>>(hsb, Wcomb, qkv, 4096, 3072, 2048);
  }

  // 6. V transpose
  {
    dim3 gv(16, 64, 2);
    k_transpose_v<<<gv, 256, 0, stream>>>(qkv, vT);
  }

  // 7. per-(b,n) mean of V
  k_vmean2<<<1024, 256, 0, stream>>>(vT, vmean);

  // 8. flash attention with dynamic mask
  k_attn<<<512, 256, 0, stream>>>(qkv, biasb, vT, vmean, ob);

  // 9. output projection (fp32 out)
  {
    dim3 go(2048 / 128, 4096 / 128);
    k_gemm_bt<0><<<go, 256, 0, stream>>>(ob, Wot, out, 4096, 2048, 2048);
  }
}

// Round 4
// 436.800 us; speedup vs baseline: 1.4160x; 1.4160x over previous
//
#include <hip/hip_runtime.h>
#include <hip/hip_bf16.h>
#include <cmath>
#include <cstdint>

typedef __attribute__((ext_vector_type(8))) short short8;
typedef __attribute__((ext_vector_type(4))) float floatx4;
typedef __attribute__((ext_vector_type(4))) unsigned int uintx4;

typedef const __attribute__((address_space(1))) unsigned int* gas_p;
typedef __attribute__((address_space(3))) unsigned int* las_p;

#define LOG2E 1.4426950408889634f

__device__ inline unsigned short f2bf(float f) {
  unsigned int u = __builtin_bit_cast(unsigned int, f);
  unsigned int r = (u + 0x7FFFu + ((u >> 16) & 1u)) >> 16;
  return (unsigned short)r;
}
__device__ inline float bf2f(unsigned short h) {
  unsigned int u = ((unsigned int)h) << 16;
  return __builtin_bit_cast(float, u);
}

// ---------------- elementwise fp32 -> bf16 (float4 loads) ----------------
__global__ void k_f32_to_bf16(const float* __restrict__ in, unsigned short* __restrict__ out, int n4) {
  int i = blockIdx.x * 256 + threadIdx.x;
  if (i >= n4) return;
  float4 v = reinterpret_cast<const float4*>(in)[i];
  uint2 o;
  o.x = (unsigned)f2bf(v.x) | ((unsigned)f2bf(v.y) << 16);
  o.y = (unsigned)f2bf(v.z) | ((unsigned)f2bf(v.w) << 16);
  reinterpret_cast<uint2*>(out)[i] = o;
}

// ---------------- transpose + convert + scale: fp32 [K][N] -> bf16 [N][K] ----------------
__global__ void k_transpose_w(const float* __restrict__ in, unsigned short* __restrict__ out,
                              int K, int N, float scl) {
  __shared__ float t[32][33];
  int n0 = blockIdx.x * 32, k0 = blockIdx.y * 32;
  int tx = threadIdx.x & 31, ty = threadIdx.x >> 5; // 256 threads: ty 0..7
  #pragma unroll
  for (int r = ty; r < 32; r += 8)
    t[r][tx] = in[(long)(k0 + r) * N + n0 + tx];
  __syncthreads();
  #pragma unroll
  for (int r = ty; r < 32; r += 8)
    out[(long)(n0 + r) * K + k0 + tx] = f2bf(t[tx][r] * scl);
}

// ---------------- small fp32 GEMM: out[d][0..3] = W[d,:] @ Ws (Kw x 4) ----------------
__global__ void k_wproj(const float* __restrict__ W, const float* __restrict__ Ws,
                        float* __restrict__ out, int Kw) {
  int d = blockIdx.x;
  float a0 = 0, a1 = 0, a2 = 0, a3 = 0;
  for (int j = threadIdx.x; j < Kw; j += 256) {
    float w = W[(long)d * Kw + j];
    float4 g = reinterpret_cast<const float4*>(Ws)[j];
    a0 += w * g.x; a1 += w * g.y; a2 += w * g.z; a3 += w * g.w;
  }
  #pragma unroll
  for (int off = 1; off < 64; off <<= 1) {
    a0 += __shfl_xor(a0, off, 64); a1 += __shfl_xor(a1, off, 64);
    a2 += __shfl_xor(a2, off, 64); a3 += __shfl_xor(a3, off, 64);
  }
  __shared__ float red[4][4];
  if ((threadIdx.x & 63) == 0) {
    int wv = threadIdx.x >> 6;
    red[wv][0] = a0; red[wv][1] = a1; red[wv][2] = a2; red[wv][3] = a3;
  }
  __syncthreads();
  if (threadIdx.x < 4) {
    int nn = threadIdx.x;
    out[d * 4 + nn] = red[0][nn] + red[1][nn] + red[2][nn] + red[3][nn];
  }
}

// ---------------- bias (fp32), pre-masked + log2e-scaled ----------------
__global__ void k_bias(const float* __restrict__ hs, const float* __restrict__ Wqg,
                       const float* __restrict__ Wvd, float* __restrict__ bias) {
  int row = blockIdx.x;           // b*2048 + s
  int b = row >> 11, s = row & 2047;
  float g0 = 0, g1 = 0, g2 = 0, g3 = 0, d0 = 0, d1 = 0, d2 = 0, d3 = 0;
  const float* h = hs + (long)row * 2048;
  for (int j = threadIdx.x; j < 2048; j += 256) {
    float x = h[j];
    float4 a = reinterpret_cast<const float4*>(Wqg)[j];
    float4 c = reinterpret_cast<const float4*>(Wvd)[j];
    g0 += x * a.x; g1 += x * a.y; g2 += x * a.z; g3 += x * a.w;
    d0 += x * c.x; d1 += x * c.y; d2 += x * c.z; d3 += x * c.w;
  }
  #pragma unroll
  for (int off = 1; off < 64; off <<= 1) {
    g0 += __shfl_xor(g0, off, 64); g1 += __shfl_xor(g1, off, 64);
    g2 += __shfl_xor(g2, off, 64); g3 += __shfl_xor(g3, off, 64);
    d0 += __shfl_xor(d0, off, 64); d1 += __shfl_xor(d1, off, 64);
    d2 += __shfl_xor(d2, off, 64); d3 += __shfl_xor(d3, off, 64);
  }
  __shared__ float red[4][8];
  if ((threadIdx.x & 63) == 0) {
    int wv = threadIdx.x >> 6;
    red[wv][0] = g0; red[wv][1] = g1; red[wv][2] = g2; red[wv][3] = g3;
    red[wv][4] = d0; red[wv][5] = d1; red[wv][6] = d2; red[wv][7] = d3;
  }
  __syncthreads();
  if (threadIdx.x < 4) {
    int nn = threadIdx.x;
    float gg = red[0][nn] + red[1][nn] + red[2][nn] + red[3][nn];
    float dd = red[0][4 + nn] + red[1][4 + nn] + red[2][4 + nn] + red[3][4 + nn];
    float sig = 1.0f / (1.0f + __expf(-gg));
    float v = sig * dd;
    bias[(b * 4 + nn) * 2048 + s] = (v > 0.0f) ? v * LOG2E : -INFINITY;
  }
}

// ---------------- bf16 MFMA GEMM: C[M,N] = A[M,K] @ Bt[N,K]^T ----------------
template <int WRITE_BF16>
__global__ __launch_bounds__(256, 2) void k_gemm_bt(
    const unsigned short* __restrict__ A, const unsigned short* __restrict__ Bt,
    void* __restrict__ Cout, int M, int N, int K) {
  __shared__ __align__(16) unsigned short As[128 * 32];
  __shared__ __align__(16) unsigned short Bs[128 * 32];
  const int tid = threadIdx.x;
  const int lane = tid & 63, wave = tid >> 6;
  const int quad = lane >> 4, l16 = lane & 15;
  const long bm = (long)blockIdx.y * 128, bn = (long)blockIdx.x * 128;
  const int wm = (wave >> 1) * 64, wn = (wave & 1) * 64;

  const floatx4 fz = {0.f, 0.f, 0.f, 0.f};
  floatx4 acc[4][4];
  #pragma unroll
  for (int i = 0; i < 4; i++)
    #pragma unroll
    for (int j = 0; j < 4; j++) acc[i][j] = fz;

  const int r0 = tid >> 2, c0 = (tid & 3) * 8;
  const unsigned short* Ag = A + (bm + r0) * K + c0;
  const unsigned short* Bg = Bt + (bn + r0) * K + c0;
  unsigned short* AsW0 = As + (wave * 16) * 32;
  unsigned short* AsW1 = As + (wave * 16 + 64) * 32;
  unsigned short* BsW0 = Bs + (wave * 16) * 32;
  unsigned short* BsW1 = Bs + (wave * 16 + 64) * 32;

  for (int kt = 0; kt < K; kt += 32) {
    __syncthreads();
    __builtin_amdgcn_global_load_lds((gas_p)(const void*)(Ag + kt),
                                     (las_p)(void*)AsW0, 16, 0, 0);
    __builtin_amdgcn_global_load_lds((gas_p)(const void*)(Ag + (long)64 * K + kt),
                                     (las_p)(void*)AsW1, 16, 0, 0);
    __builtin_amdgcn_global_load_lds((gas_p)(const void*)(Bg + kt),
                                     (las_p)(void*)BsW0, 16, 0, 0);
    __builtin_amdgcn_global_load_lds((gas_p)(const void*)(Bg + (long)64 * K + kt),
                                     (las_p)(void*)BsW1, 16, 0, 0);
    __syncthreads();
    short8 af[4], bf[4];
    #pragma unroll
    for (int i = 0; i < 4; i++)
      af[i] = *reinterpret_cast<const short8*>(&As[(wm + i * 16 + l16) * 32 + quad * 8]);
    #pragma unroll
    for (int j = 0; j < 4; j++)
      bf[j] = *reinterpret_cast<const short8*>(&Bs[(wn + j * 16 + l16) * 32 + quad * 8]);
    #pragma unroll
    for (int i = 0; i < 4; i++)
      #pragma unroll
      for (int j = 0; j < 4; j++)
        acc[i][j] = __builtin_amdgcn_mfma_f32_16x16x32_bf16(af[i], bf[j], acc[i][j], 0, 0, 0);
  }
  #pragma unroll
  for (int i = 0; i < 4; i++)
    #pragma unroll
    for (int j = 0; j < 4; j++)
      #pragma unroll
      for (int r = 0; r < 4; r++) {
        const long row = bm + wm + i * 16 + quad * 4 + r;
        const long col = bn + wn + j * 16 + l16;
        const float v = acc[i][j][r];
        if (WRITE_BF16)
          ((unsigned short*)Cout)[row * N + col] = f2bf(v);
        else
          ((float*)Cout)[row * N + col] = v;
      }
}

// ---------------- bf16 transpose of V slice ----------------
__global__ void k_transpose_v(const unsigned short* __restrict__ qkv, unsigned short* __restrict__ vt) {
  __shared__ unsigned short t[32][33];
  int c0 = blockIdx.x * 32, s0 = blockIdx.y * 32, b = blockIdx.z;
  int tx = threadIdx.x & 31, ty = threadIdx.x >> 5;
  #pragma unroll
  for (int r = ty; r < 32; r += 8)
    t[r][tx] = qkv[((long)(b * 2048 + s0 + r)) * 3072 + 2560 + c0 + tx];
  __syncthreads();
  #pragma unroll
  for (int r = ty; r < 32; r += 8)
    vt[((long)(b * 512 + c0 + r)) * 2048 + s0 + tx] = t[tx][r];
}

// ---------------- vmean from vT rows (coalesced) ----------------
__global__ void k_vmean2(const unsigned short* __restrict__ vT, float* __restrict__ vmean) {
  const int row = blockIdx.x;  // 1024
  const int tid = threadIdx.x, lane = tid & 63, wave = tid >> 6;
  uintx4 v = reinterpret_cast<const uintx4*>(vT + (long)row * 2048)[tid];
  float s = 0.f;
  #pragma unroll
  for (int i = 0; i < 4; i++) {
    unsigned u = v[i];
    s += bf2f((unsigned short)(u & 0xffff)) + bf2f((unsigned short)(u >> 16));
  }
  #pragma unroll
  for (int off = 1; off < 64; off <<= 1) s += __shfl_xor(s, off, 64);
  __shared__ float red[4];
  if (lane == 0) red[wave] = s;
  __syncthreads();
  if (tid == 0) vmean[row] = (red[0] + red[1] + red[2] + red[3]) * (1.0f / 2048.0f);
}

// ---------------- online-softmax 16-row tile update ----------------
template <bool FULL>
__device__ __forceinline__ void softmax16(
    floatx4 (&sacc)[4], floatx4 (&oacc)[8],
    float (&mrow)[4], float (&lrow)[4],
    const float (&bcol)[4], int q0, int k0, int quad, int l16) {
  #pragma unroll
  for (int r = 0; r < 4; r++) {
    const int qrow = q0 + quad * 4 + r;
    float mx = -INFINITY;
    #pragma unroll
    for (int nt = 0; nt < 4; nt++) {
      float x = sacc[nt][r] + bcol[nt];  // bcol pre-masked (-INF) + log2e-scaled
      if (!FULL) {
        const int key = k0 + nt * 16 + l16;
        x = (key <= qrow) ? x : -INFINITY;
      }
      sacc[nt][r] = x;
      mx = fmaxf(mx, x);
    }
    mx = fmaxf(mx, __shfl_xor(mx, 1, 64));
    mx = fmaxf(mx, __shfl_xor(mx, 2, 64));
    mx = fmaxf(mx, __shfl_xor(mx, 4, 64));
    mx = fmaxf(mx, __shfl_xor(mx, 8, 64));
    const float mn = fmaxf(mrow[r], mx);
    const float mnc = fmaxf(mn, -1e38f);     // clamp: fully-masked rows -> exp2 gives 0, no NaN
    const float alpha = __builtin_amdgcn_exp2f(mrow[r] - mnc);
    float rs = 0.0f;
    #pragma unroll
    for (int nt = 0; nt < 4; nt++) {
      float p = __builtin_amdgcn_exp2f(sacc[nt][r] - mnc);
      sacc[nt][r] = p;
      rs += p;
    }
    rs += __shfl_xor(rs, 1, 64);
    rs += __shfl_xor(rs, 2, 64);
    rs += __shfl_xor(rs, 4, 64);
    rs += __shfl_xor(rs, 8, 64);
    mrow[r] = mn;
    lrow[r] = lrow[r] * alpha + rs;
    #pragma unroll
    for (int j = 0; j < 8; j++) oacc[j][r] *= alpha;
  }
}

// ---------------- flash attention with dynamic mask ----------------
// grid 1024 = qt(32, reversed/LPT) x b(2) x n(4) x g(4); 4 waves; wave owns 16 q rows.
// Register diet vs R3: 16-row wave tile -> ~110 unified regs, fits 3-wave bound w/o spills.
// LDS: Ks(64x144, overlaid by per-wave Ps 16x72 after barrier 3) + Vs(128x72) = 36,864 B -> 4 blocks/CU.
__global__ __launch_bounds__(256, 3) void k_attn(
    const unsigned short* __restrict__ qkv,  // [4096][3072] (q | k | v); q pre-scaled by scale*log2e
    const float* __restrict__ biasb,         // [8][2048] pre-masked, log2e-scaled
    const unsigned short* __restrict__ vT,   // [1024][2048]
    const float* __restrict__ vmean,         // [1024]
    unsigned short* __restrict__ o)          // [4096][2048]
{
  int idx = blockIdx.x;
  const int g = idx & 3;
  const int n = (idx >> 2) & 3;
  const int b = (idx >> 4) & 1;
  const int qt = 31 - (idx >> 5);            // 64-row q tiles, big blocks dispatch first (LPT)
  const int tid = threadIdx.x, lane = tid & 63, wave = tid >> 6;
  const int quad = lane >> 4, l16 = lane & 15;
  const int q0 = qt * 64 + wave * 16;

  __shared__ __align__(16) unsigned short KPs[64 * 144]; // K tile; overlaid by P after barrier(3)
  __shared__ __align__(16) unsigned short Vs[128 * 72];  // [hd][key]
  unsigned short* Psw = KPs + wave * 1152;               // 16 x 72, per-wave private

  // Q fragments (A-operand): row = q0+l16, k = ks*32+quad*8..+8
  short8 qf[4];
  {
    const unsigned short* qp = qkv + (long)(b * 2048) * 3072 + (n * 4 + g) * 128;
    #pragma unroll
    for (int ks = 0; ks < 4; ks++)
      qf[ks] = *reinterpret_cast<const short8*>(
          qp + (long)(q0 + l16) * 3072 + ks * 32 + quad * 8);
  }

  const floatx4 fz = {0.f, 0.f, 0.f, 0.f};
  floatx4 oacc[8];
  #pragma unroll
  for (int j = 0; j < 8; j++) oacc[j] = fz;
  float mrow[4], lrow[4];
  #pragma unroll
  for (int r = 0; r < 4; r++) { mrow[r] = -INFINITY; lrow[r] = 0.0f; }

  const float* biasrow = biasb + (b * 4 + n) * 2048;
  const int kend = qt * 64 + 64;
  for (int k0 = 0; k0 < kend; k0 += 64) {
    __syncthreads();  // (1) prev-iter P/V LDS reads complete
    {
      const unsigned short* kp = qkv + (long)(b * 2048 + k0) * 3072 + 2048 + n * 128;
      #pragma unroll
      for (int it = 0; it < 4; it++) {
        int seg = tid + it * 256;
        int kk = seg >> 4, hdo = (seg & 15) * 8;
        *reinterpret_cast<uintx4*>(&KPs[kk * 144 + hdo]) =
            *reinterpret_cast<const uintx4*>(kp + (long)kk * 3072 + hdo);
      }
      const unsigned short* vp = vT + (long)(b * 512 + n * 128) * 2048 + k0;
      #pragma unroll
      for (int it = 0; it < 4; it++) {
        int seg = tid + it * 256;
        int hd = seg >> 3, ko = (seg & 7) * 8;
        *reinterpret_cast<uintx4*>(&Vs[hd * 72 + ko]) =
            *reinterpret_cast<const uintx4*>(vp + (long)hd * 2048 + ko);
      }
    }
    __syncthreads();  // (2) staging visible

    const bool active = (k0 <= q0 + 15);  // any key of this tile usable by this wave?
    floatx4 sacc[4];
    float bcol[4];
    if (active) {
      #pragma unroll
      for (int nt = 0; nt < 4; nt++) bcol[nt] = biasrow[k0 + nt * 16 + l16];
      #pragma unroll
      for (int nt = 0; nt < 4; nt++) sacc[nt] = fz;
      #pragma unroll
      for (int ks = 0; ks < 4; ks++) {
        short8 kf[4];
        #pragma unroll
        for (int nt = 0; nt < 4; nt++)
          kf[nt] = *reinterpret_cast<const short8*>(&KPs[(nt * 16 + l16) * 144 + ks * 32 + quad * 8]);
        #pragma unroll
        for (int nt = 0; nt < 4; nt++)
          sacc[nt] = __builtin_amdgcn_mfma_f32_16x16x32_bf16(qf[ks], kf[nt], sacc[nt], 0, 0, 0);
      }
    }
    __syncthreads();  // (3) ALL waves done reading K tile; P may now overlay it

    if (active) {
      const bool full = (k0 + 63 <= q0);  // tile entirely below diagonal for this wave
      if (full)
        softmax16<true>(sacc, oacc, mrow, lrow, bcol, q0, k0, quad, l16);
      else
        softmax16<false>(sacc, oacc, mrow, lrow, bcol, q0, k0, quad, l16);

      // P (C-layout) -> per-wave LDS -> A-layout; wave-private, no barrier
      #pragma unroll
      for (int nt = 0; nt < 4; nt++)
        #pragma unroll
        for (int r = 0; r < 4; r++)
          Psw[(quad * 4 + r) * 72 + nt * 16 + l16] = f2bf(sacc[nt][r]);

      // O += P @ V
      #pragma unroll
      for (int ks2 = 0; ks2 < 2; ks2++) {
        short8 pf = *reinterpret_cast<const short8*>(&Psw[l16 * 72 + ks2 * 32 + quad * 8]);
        #pragma unroll
        for (int j = 0; j < 8; j++) {
          short8 vf = *reinterpret_cast<const short8*>(&Vs[(j * 16 + l16) * 72 + ks2 * 32 + quad * 8]);
          oacc[j] = __builtin_amdgcn_mfma_f32_16x16x32_bf16(pf, vf, oacc[j], 0, 0, 0);
        }
      }
    }
  }

  // epilogue
  const long obase = (long)(b * 2048) * 2048 + (n * 4 + g) * 128;
  #pragma unroll
  for (int r = 0; r < 4; r++) {
    const int qrow = q0 + quad * 4 + r;
    const float l = lrow[r];
    const float inv = (l > 0.0f) ? 1.0f / l : 0.0f;
    #pragma unroll
    for (int j = 0; j < 8; j++) {
      const int hd = j * 16 + l16;
      float v = oacc[j][r] * inv;
      if (l <= 0.0f) v = vmean[(b * 4 + n) * 128 + hd];  // empty row: uniform softmax over ALL keys
      o[obase + (long)qrow * 2048 + hd] = f2bf(v);
    }
  }
}

extern "C" void kernel_launch(void* const* d_in, const int* in_sizes, int n_in,
                              void* d_out, int out_size, void* d_ws, size_t ws_size,
                              hipStream_t stream) {
  const float* hs = (const float*)d_in[0];
  const float* Wq = (const float*)d_in[1];
  const float* Wk = (const float*)d_in[2];
  const float* Wv = (const float*)d_in[3];
  const float* Wg = (const float*)d_in[4];
  const float* Wd = (const float*)d_in[5];
  const float* Wo = (const float*)d_in[6];
  float* out = (float*)d_out;

  char* ws = (char*)d_ws;
  unsigned short* hsb   = (unsigned short*)(ws);               // 16,777,216 B
  unsigned short* Wcomb = (unsigned short*)(ws + 16777216);    // 12,582,912 B  [3072][2048]
  unsigned short* Wot   = (unsigned short*)(ws + 29360128);    //  8,388,608 B
  float*  Wqg   = (float*)(ws + 37748736);                     //     32,768 B
  float*  Wvd   = (float*)(ws + 37781504);                     //     32,768 B
  float*  biasb = (float*)(ws + 37814272);                     //     65,536 B
  unsigned short* qkv = (unsigned short*)(ws + 37879808);      // 25,165,824 B  [4096][3072]
  unsigned short* vT  = (unsigned short*)(ws + 63045632);      //  4,194,304 B
  float*  vmean = (float*)(ws + 67239936);                     //      4,096 B
  unsigned short* ob  = (unsigned short*)(ws + 67244032);      // 16,777,216 B

  const float QSCALE = 0.08838834764831845f * LOG2E;  // fold softmax scale + log2e into Q

  // 1. hs -> bf16
  k_f32_to_bf16<<<2097152 / 256, 256, 0, stream>>>(hs, hsb, 2097152);

  // 2. weight transposes (fp32 -> bf16, B^T layout); Wq pre-scaled
  {
    dim3 g1(2048 / 32, 2048 / 32);
    dim3 g2(512 / 32, 2048 / 32);
    k_transpose_w<<<g1, 256, 0, stream>>>(Wq, Wcomb, 2048, 2048, QSCALE);
    k_transpose_w<<<g2, 256, 0, stream>>>(Wk, Wcomb + (long)2048 * 2048, 2048, 512, 1.0f);
    k_transpose_w<<<g2, 256, 0, stream>>>(Wv, Wcomb + (long)2560 * 2048, 2048, 512, 1.0f);
    k_transpose_w<<<g1, 256, 0, stream>>>(Wo, Wot, 2048, 2048, 1.0f);
  }

  // 3. fused weight products for fp32 gate/delta path
  k_wproj<<<2048, 256, 0, stream>>>(Wq, Wg, Wqg, 2048);
  k_wproj<<<2048, 256, 0, stream>>>(Wv, Wd, Wvd, 512);

  // 4. bias (fp32): pre-masked + log2e-scaled
  k_bias<<<4096, 256, 0, stream>>>(hs, Wqg, Wvd, biasb);

  // 5. fused QKV projection GEMM
  {
    dim3 gq(3072 / 128, 4096 / 128);
    k_gemm_bt<1><<<gq, 256, 0, stream>>>(hsb, Wcomb, qkv, 4096, 3072, 2048);
  }

  // 6. V transpose
  {
    dim3 gv(16, 64, 2);
    k_transpose_v<<<gv, 256, 0, stream>>>(qkv, vT);
  }

  // 7. per-(b,n) mean of V
  k_vmean2<<<1024, 256, 0, stream>>>(vT, vmean);

  // 8. flash attention with dynamic mask (1024 blocks, 64-row q tiles)
  k_attn<<<1024, 256, 0, stream>>>(qkv, biasb, vT, vmean, ob);

  // 9. output projection (fp32 out)
  {
    dim3 go(2048 / 128, 4096 / 128);
    k_gemm_bt<0><<<go, 256, 0, stream>>>(ob, Wot, out, 4096, 2048, 2048);
  }
}

// Round 5
// 414.723 us; speedup vs baseline: 1.4914x; 1.0532x over previous
//
#include <hip/hip_runtime.h>
#include <hip/hip_bf16.h>
#include <cmath>
#include <cstdint>

typedef __attribute__((ext_vector_type(8))) short short8;
typedef __attribute__((ext_vector_type(4))) float floatx4;
typedef __attribute__((ext_vector_type(4))) unsigned int uintx4;

typedef const __attribute__((address_space(1))) unsigned int* gas_p;
typedef __attribute__((address_space(3))) unsigned int* las_p;

#define LOG2E 1.4426950408889634f

__device__ inline unsigned short f2bf(float f) {
  unsigned int u = __builtin_bit_cast(unsigned int, f);
  unsigned int r = (u + 0x7FFFu + ((u >> 16) & 1u)) >> 16;
  return (unsigned short)r;
}
__device__ inline float bf2f(unsigned short h) {
  unsigned int u = ((unsigned int)h) << 16;
  return __builtin_bit_cast(float, u);
}

// ---------------- elementwise fp32 -> bf16 (float4 loads) ----------------
__global__ void k_f32_to_bf16(const float* __restrict__ in, unsigned short* __restrict__ out, int n4) {
  int i = blockIdx.x * 256 + threadIdx.x;
  if (i >= n4) return;
  float4 v = reinterpret_cast<const float4*>(in)[i];
  uint2 o;
  o.x = (unsigned)f2bf(v.x) | ((unsigned)f2bf(v.y) << 16);
  o.y = (unsigned)f2bf(v.z) | ((unsigned)f2bf(v.w) << 16);
  reinterpret_cast<uint2*>(out)[i] = o;
}

// ---------------- transpose + convert + scale: fp32 [K][N] -> bf16 [N][K] ----------------
__global__ void k_transpose_w(const float* __restrict__ in, unsigned short* __restrict__ out,
                              int K, int N, float scl) {
  __shared__ float t[32][33];
  int n0 = blockIdx.x * 32, k0 = blockIdx.y * 32;
  int tx = threadIdx.x & 31, ty = threadIdx.x >> 5; // 256 threads: ty 0..7
  #pragma unroll
  for (int r = ty; r < 32; r += 8)
    t[r][tx] = in[(long)(k0 + r) * N + n0 + tx];
  __syncthreads();
  #pragma unroll
  for (int r = ty; r < 32; r += 8)
    out[(long)(n0 + r) * K + k0 + tx] = f2bf(t[tx][r] * scl);
}

// ---------------- small fp32 GEMM: out[d][0..3] = W[d,:] @ Ws (Kw x 4) ----------------
__global__ void k_wproj(const float* __restrict__ W, const float* __restrict__ Ws,
                        float* __restrict__ out, int Kw) {
  int d = blockIdx.x;
  float a0 = 0, a1 = 0, a2 = 0, a3 = 0;
  for (int j = threadIdx.x; j < Kw; j += 256) {
    float w = W[(long)d * Kw + j];
    float4 g = reinterpret_cast<const float4*>(Ws)[j];
    a0 += w * g.x; a1 += w * g.y; a2 += w * g.z; a3 += w * g.w;
  }
  #pragma unroll
  for (int off = 1; off < 64; off <<= 1) {
    a0 += __shfl_xor(a0, off, 64); a1 += __shfl_xor(a1, off, 64);
    a2 += __shfl_xor(a2, off, 64); a3 += __shfl_xor(a3, off, 64);
  }
  __shared__ float red[4][4];
  if ((threadIdx.x & 63) == 0) {
    int wv = threadIdx.x >> 6;
    red[wv][0] = a0; red[wv][1] = a1; red[wv][2] = a2; red[wv][3] = a3;
  }
  __syncthreads();
  if (threadIdx.x < 4) {
    int nn = threadIdx.x;
    out[d * 4 + nn] = red[0][nn] + red[1][nn] + red[2][nn] + red[3][nn];
  }
}

// ---------------- bias (fp32), pre-masked + log2e-scaled ----------------
__global__ void k_bias(const float* __restrict__ hs, const float* __restrict__ Wqg,
                       const float* __restrict__ Wvd, float* __restrict__ bias) {
  int row = blockIdx.x;           // b*2048 + s
  int b = row >> 11, s = row & 2047;
  float g0 = 0, g1 = 0, g2 = 0, g3 = 0, d0 = 0, d1 = 0, d2 = 0, d3 = 0;
  const float* h = hs + (long)row * 2048;
  for (int j = threadIdx.x; j < 2048; j += 256) {
    float x = h[j];
    float4 a = reinterpret_cast<const float4*>(Wqg)[j];
    float4 c = reinterpret_cast<const float4*>(Wvd)[j];
    g0 += x * a.x; g1 += x * a.y; g2 += x * a.z; g3 += x * a.w;
    d0 += x * c.x; d1 += x * c.y; d2 += x * c.z; d3 += x * c.w;
  }
  #pragma unroll
  for (int off = 1; off < 64; off <<= 1) {
    g0 += __shfl_xor(g0, off, 64); g1 += __shfl_xor(g1, off, 64);
    g2 += __shfl_xor(g2, off, 64); g3 += __shfl_xor(g3, off, 64);
    d0 += __shfl_xor(d0, off, 64); d1 += __shfl_xor(d1, off, 64);
    d2 += __shfl_xor(d2, off, 64); d3 += __shfl_xor(d3, off, 64);
  }
  __shared__ float red[4][8];
  if ((threadIdx.x & 63) == 0) {
    int wv = threadIdx.x >> 6;
    red[wv][0] = g0; red[wv][1] = g1; red[wv][2] = g2; red[wv][3] = g3;
    red[wv][4] = d0; red[wv][5] = d1; red[wv][6] = d2; red[wv][7] = d3;
  }
  __syncthreads();
  if (threadIdx.x < 4) {
    int nn = threadIdx.x;
    float gg = red[0][nn] + red[1][nn] + red[2][nn] + red[3][nn];
    float dd = red[0][4 + nn] + red[1][4 + nn] + red[2][4 + nn] + red[3][4 + nn];
    float sig = 1.0f / (1.0f + __expf(-gg));
    float v = sig * dd;
    bias[(b * 4 + nn) * 2048 + s] = (v > 0.0f) ? v * LOG2E : -INFINITY;
  }
}

// ---------------- bf16 MFMA GEMM: C[M,N] = A[M,K] @ Bt[N,K]^T ----------------
template <int WRITE_BF16>
__global__ __launch_bounds__(256, 2) void k_gemm_bt(
    const unsigned short* __restrict__ A, const unsigned short* __restrict__ Bt,
    void* __restrict__ Cout, int M, int N, int K) {
  __shared__ __align__(16) unsigned short As[128 * 32];
  __shared__ __align__(16) unsigned short Bs[128 * 32];
  const int tid = threadIdx.x;
  const int lane = tid & 63, wave = tid >> 6;
  const int quad = lane >> 4, l16 = lane & 15;
  const long bm = (long)blockIdx.y * 128, bn = (long)blockIdx.x * 128;
  const int wm = (wave >> 1) * 64, wn = (wave & 1) * 64;

  const floatx4 fz = {0.f, 0.f, 0.f, 0.f};
  floatx4 acc[4][4];
  #pragma unroll
  for (int i = 0; i < 4; i++)
    #pragma unroll
    for (int j = 0; j < 4; j++) acc[i][j] = fz;

  const int r0 = tid >> 2, c0 = (tid & 3) * 8;
  const unsigned short* Ag = A + (bm + r0) * K + c0;
  const unsigned short* Bg = Bt + (bn + r0) * K + c0;
  unsigned short* AsW0 = As + (wave * 16) * 32;
  unsigned short* AsW1 = As + (wave * 16 + 64) * 32;
  unsigned short* BsW0 = Bs + (wave * 16) * 32;
  unsigned short* BsW1 = Bs + (wave * 16 + 64) * 32;

  for (int kt = 0; kt < K; kt += 32) {
    __syncthreads();
    __builtin_amdgcn_global_load_lds((gas_p)(const void*)(Ag + kt),
                                     (las_p)(void*)AsW0, 16, 0, 0);
    __builtin_amdgcn_global_load_lds((gas_p)(const void*)(Ag + (long)64 * K + kt),
                                     (las_p)(void*)AsW1, 16, 0, 0);
    __builtin_amdgcn_global_load_lds((gas_p)(const void*)(Bg + kt),
                                     (las_p)(void*)BsW0, 16, 0, 0);
    __builtin_amdgcn_global_load_lds((gas_p)(const void*)(Bg + (long)64 * K + kt),
                                     (las_p)(void*)BsW1, 16, 0, 0);
    __syncthreads();
    short8 af[4], bf[4];
    #pragma unroll
    for (int i = 0; i < 4; i++)
      af[i] = *reinterpret_cast<const short8*>(&As[(wm + i * 16 + l16) * 32 + quad * 8]);
    #pragma unroll
    for (int j = 0; j < 4; j++)
      bf[j] = *reinterpret_cast<const short8*>(&Bs[(wn + j * 16 + l16) * 32 + quad * 8]);
    #pragma unroll
    for (int i = 0; i < 4; i++)
      #pragma unroll
      for (int j = 0; j < 4; j++)
        acc[i][j] = __builtin_amdgcn_mfma_f32_16x16x32_bf16(af[i], bf[j], acc[i][j], 0, 0, 0);
  }
  #pragma unroll
  for (int i = 0; i < 4; i++)
    #pragma unroll
    for (int j = 0; j < 4; j++)
      #pragma unroll
      for (int r = 0; r < 4; r++) {
        const long row = bm + wm + i * 16 + quad * 4 + r;
        const long col = bn + wn + j * 16 + l16;
        const float v = acc[i][j][r];
        if (WRITE_BF16)
          ((unsigned short*)Cout)[row * N + col] = f2bf(v);
        else
          ((float*)Cout)[row * N + col] = v;
      }
}

// ---------------- bf16 transpose of V slice ----------------
__global__ void k_transpose_v(const unsigned short* __restrict__ qkv, unsigned short* __restrict__ vt) {
  __shared__ unsigned short t[32][33];
  int c0 = blockIdx.x * 32, s0 = blockIdx.y * 32, b = blockIdx.z;
  int tx = threadIdx.x & 31, ty = threadIdx.x >> 5;
  #pragma unroll
  for (int r = ty; r < 32; r += 8)
    t[r][tx] = qkv[((long)(b * 2048 + s0 + r)) * 3072 + 2560 + c0 + tx];
  __syncthreads();
  #pragma unroll
  for (int r = ty; r < 32; r += 8)
    vt[((long)(b * 512 + c0 + r)) * 2048 + s0 + tx] = t[tx][r];
}

// ---------------- vmean from vT rows (coalesced) ----------------
__global__ void k_vmean2(const unsigned short* __restrict__ vT, float* __restrict__ vmean) {
  const int row = blockIdx.x;  // 1024
  const int tid = threadIdx.x, lane = tid & 63, wave = tid >> 6;
  uintx4 v = reinterpret_cast<const uintx4*>(vT + (long)row * 2048)[tid];
  float s = 0.f;
  #pragma unroll
  for (int i = 0; i < 4; i++) {
    unsigned u = v[i];
    s += bf2f((unsigned short)(u & 0xffff)) + bf2f((unsigned short)(u >> 16));
  }
  #pragma unroll
  for (int off = 1; off < 64; off <<= 1) s += __shfl_xor(s, off, 64);
  __shared__ float red[4];
  if (lane == 0) red[wave] = s;
  __syncthreads();
  if (tid == 0) vmean[row] = (red[0] + red[1] + red[2] + red[3]) * (1.0f / 2048.0f);
}

// ---------------- flash attention with dynamic mask (transposed scores) ----------------
// S^T = K @ Q^T: C-layout gives col(l16)=q-row, row(quad*4+r)=key ->
// softmax reduces over keys IN-LANE (15 max/add) + 2 shfl_xor(16,32); m/l state per-lane.
// alpha/l transposed to oacc's q-space (quad*4+r) via 4 bpermutes.
// grid 1024 = qt(32, LPT) x b(2) x n(4) x g(4); 4 waves; wave owns 16 q rows.
__global__ __launch_bounds__(256, 3) void k_attn(
    const unsigned short* __restrict__ qkv,  // [4096][3072] (q | k | v); q pre-scaled by scale*log2e
    const float* __restrict__ biasb,         // [8][2048] pre-masked (-INF), log2e-scaled
    const unsigned short* __restrict__ vT,   // [1024][2048]
    const float* __restrict__ vmean,         // [1024]
    unsigned short* __restrict__ o)          // [4096][2048]
{
  int idx = blockIdx.x;
  const int g = idx & 3;
  const int n = (idx >> 2) & 3;
  const int b = (idx >> 4) & 1;
  const int qt = 31 - (idx >> 5);            // 64-row q tiles, big blocks dispatch first (LPT)
  const int tid = threadIdx.x, lane = tid & 63, wave = tid >> 6;
  const int quad = lane >> 4, l16 = lane & 15;
  const int q0 = qt * 64 + wave * 16;

  __shared__ __align__(16) unsigned short KPs[64 * 144]; // K tile; overlaid by P after barrier(3)
  __shared__ __align__(16) unsigned short Vs[128 * 72];  // [hd][key]
  unsigned short* Psw = KPs + wave * 1152;               // 16 x 72 [q][key], per-wave private

  // Q fragments (B-operand for K@Q^T; layout identical to A-operand): row=q0+l16, k=ks*32+quad*8..+8
  short8 qf[4];
  {
    const unsigned short* qp = qkv + (long)(b * 2048) * 3072 + (n * 4 + g) * 128;
    #pragma unroll
    for (int ks = 0; ks < 4; ks++)
      qf[ks] = *reinterpret_cast<const short8*>(
          qp + (long)(q0 + l16) * 3072 + ks * 32 + quad * 8);
  }

  const floatx4 fz = {0.f, 0.f, 0.f, 0.f};
  floatx4 oacc[8];
  #pragma unroll
  for (int j = 0; j < 8; j++) oacc[j] = fz;
  float mrow = -INFINITY, lrow = 0.0f;       // per-lane: q = q0 + l16 (replicated across quads)

  const float* biasrow = biasb + (b * 4 + n) * 2048;
  const int kend = qt * 64 + 64;
  for (int k0 = 0; k0 < kend; k0 += 64) {
    __syncthreads();  // (1) prev-iter P/V LDS reads complete
    {
      const unsigned short* kp = qkv + (long)(b * 2048 + k0) * 3072 + 2048 + n * 128;
      #pragma unroll
      for (int it = 0; it < 4; it++) {
        int seg = tid + it * 256;
        int kk = seg >> 4, hdo = (seg & 15) * 8;
        *reinterpret_cast<uintx4*>(&KPs[kk * 144 + hdo]) =
            *reinterpret_cast<const uintx4*>(kp + (long)kk * 3072 + hdo);
      }
      const unsigned short* vp = vT + (long)(b * 512 + n * 128) * 2048 + k0;
      #pragma unroll
      for (int it = 0; it < 4; it++) {
        int seg = tid + it * 256;
        int hd = seg >> 3, ko = (seg & 7) * 8;
        *reinterpret_cast<uintx4*>(&Vs[hd * 72 + ko]) =
            *reinterpret_cast<const uintx4*>(vp + (long)hd * 2048 + ko);
      }
    }
    __syncthreads();  // (2) staging visible

    const bool active = (k0 <= q0 + 15);
    unsigned pk[4][2];   // packed bf16 P, carried across barrier (3)
    float alpha = 1.0f;
    if (active) {
      // S^T tile: sacc[kt] rows = keys kt*16+quad*4+r, col = q0+l16. C-init = bias[key].
      floatx4 sacc[4];
      #pragma unroll
      for (int kt = 0; kt < 4; kt++) {
        float4 bb = *reinterpret_cast<const float4*>(biasrow + k0 + kt * 16 + quad * 4);
        sacc[kt] = (floatx4){bb.x, bb.y, bb.z, bb.w};
      }
      #pragma unroll
      for (int ks = 0; ks < 4; ks++) {
        short8 kf[4];
        #pragma unroll
        for (int kt = 0; kt < 4; kt++)
          kf[kt] = *reinterpret_cast<const short8*>(&KPs[(kt * 16 + l16) * 144 + ks * 32 + quad * 8]);
        #pragma unroll
        for (int kt = 0; kt < 4; kt++)
          sacc[kt] = __builtin_amdgcn_mfma_f32_16x16x32_bf16(kf[kt], qf[ks], sacc[kt], 0, 0, 0);
      }

      // softmax (register-only, before barrier): mask, in-lane max/sum + 2 shfls
      const bool full = (k0 + 63 <= q0);
      if (!full) {
        const int diff = (q0 + l16) - (k0 + quad * 4);  // key allowed iff kt*16+r <= diff
        #pragma unroll
        for (int kt = 0; kt < 4; kt++)
          #pragma unroll
          for (int r = 0; r < 4; r++)
            if (kt * 16 + r > diff) sacc[kt][r] = -INFINITY;
      }
      float mx = -INFINITY;
      #pragma unroll
      for (int kt = 0; kt < 4; kt++)
        #pragma unroll
        for (int r = 0; r < 4; r++) mx = fmaxf(mx, sacc[kt][r]);
      mx = fmaxf(mx, __shfl_xor(mx, 16, 64));
      mx = fmaxf(mx, __shfl_xor(mx, 32, 64));
      const float mn = fmaxf(mrow, mx);
      const float mnc = fmaxf(mn, -1e38f);
      alpha = __builtin_amdgcn_exp2f(mrow - mnc);
      float rs = 0.0f;
      #pragma unroll
      for (int kt = 0; kt < 4; kt++) {
        #pragma unroll
        for (int r = 0; r < 4; r++) {
          float p = __builtin_amdgcn_exp2f(sacc[kt][r] - mnc);
          sacc[kt][r] = p;
          rs += p;
        }
        #pragma unroll
        for (int r2 = 0; r2 < 2; r2++)
          pk[kt][r2] = (unsigned)f2bf(sacc[kt][2 * r2]) | ((unsigned)f2bf(sacc[kt][2 * r2 + 1]) << 16);
      }
      rs += __shfl_xor(rs, 16, 64);
      rs += __shfl_xor(rs, 32, 64);
      mrow = mn;
      lrow = lrow * alpha + rs;
    }
    __syncthreads();  // (3) ALL waves done reading K tile; P may now overlay it

    if (active) {
      // rescale O: alpha lives in q=l16 space; oacc rows are q=quad*4+r -> bpermute transpose
      float al[4];
      #pragma unroll
      for (int r = 0; r < 4; r++) al[r] = __shfl(alpha, quad * 4 + r, 64);
      #pragma unroll
      for (int j = 0; j < 8; j++)
        #pragma unroll
        for (int r = 0; r < 4; r++) oacc[j][r] *= al[r];

      // store packed P to Psw[q=l16][key] (dword granularity)
      unsigned* Pd = reinterpret_cast<unsigned*>(Psw);
      #pragma unroll
      for (int kt = 0; kt < 4; kt++)
        #pragma unroll
        for (int r2 = 0; r2 < 2; r2++)
          Pd[l16 * 36 + kt * 8 + quad * 2 + r2] = pk[kt][r2];

      // O += P @ V  (A = P [q][key], B = V^T [key][hd])
      #pragma unroll
      for (int ks2 = 0; ks2 < 2; ks2++) {
        short8 pf = *reinterpret_cast<const short8*>(&Psw[l16 * 72 + ks2 * 32 + quad * 8]);
        #pragma unroll
        for (int j = 0; j < 8; j++) {
          short8 vf = *reinterpret_cast<const short8*>(&Vs[(j * 16 + l16) * 72 + ks2 * 32 + quad * 8]);
          oacc[j] = __builtin_amdgcn_mfma_f32_16x16x32_bf16(pf, vf, oacc[j], 0, 0, 0);
        }
      }
    }
  }

  // epilogue: oacc rows q=q0+quad*4+r; l lives in q=l16 space -> bpermute
  const long obase = (long)(b * 2048) * 2048 + (n * 4 + g) * 128;
  #pragma unroll
  for (int r = 0; r < 4; r++) {
    const int qrow = q0 + quad * 4 + r;
    const float l = __shfl(lrow, quad * 4 + r, 64);
    const float inv = (l > 0.0f) ? 1.0f / l : 0.0f;
    #pragma unroll
    for (int j = 0; j < 8; j++) {
      const int hd = j * 16 + l16;
      float v = oacc[j][r] * inv;
      if (l <= 0.0f) v = vmean[(b * 4 + n) * 128 + hd];  // empty row: uniform softmax over ALL keys
      o[obase + (long)qrow * 2048 + hd] = f2bf(v);
    }
  }
}

extern "C" void kernel_launch(void* const* d_in, const int* in_sizes, int n_in,
                              void* d_out, int out_size, void* d_ws, size_t ws_size,
                              hipStream_t stream) {
  const float* hs = (const float*)d_in[0];
  const float* Wq = (const float*)d_in[1];
  const float* Wk = (const float*)d_in[2];
  const float* Wv = (const float*)d_in[3];
  const float* Wg = (const float*)d_in[4];
  const float* Wd = (const float*)d_in[5];
  const float* Wo = (const float*)d_in[6];
  float* out = (float*)d_out;

  char* ws = (char*)d_ws;
  unsigned short* hsb   = (unsigned short*)(ws);               // 16,777,216 B
  unsigned short* Wcomb = (unsigned short*)(ws + 16777216);    // 12,582,912 B  [3072][2048]
  unsigned short* Wot   = (unsigned short*)(ws + 29360128);    //  8,388,608 B
  float*  Wqg   = (float*)(ws + 37748736);                     //     32,768 B
  float*  Wvd   = (float*)(ws + 37781504);                     //     32,768 B
  float*  biasb = (float*)(ws + 37814272);                     //     65,536 B
  unsigned short* qkv = (unsigned short*)(ws + 37879808);      // 25,165,824 B  [4096][3072]
  unsigned short* vT  = (unsigned short*)(ws + 63045632);      //  4,194,304 B
  float*  vmean = (float*)(ws + 67239936);                     //      4,096 B
  unsigned short* ob  = (unsigned short*)(ws + 67244032);      // 16,777,216 B

  const float QSCALE = 0.08838834764831845f * LOG2E;  // fold softmax scale + log2e into Q

  // 1. hs -> bf16
  k_f32_to_bf16<<<2097152 / 256, 256, 0, stream>>>(hs, hsb, 2097152);

  // 2. weight transposes (fp32 -> bf16, B^T layout); Wq pre-scaled
  {
    dim3 g1(2048 / 32, 2048 / 32);
    dim3 g2(512 / 32, 2048 / 32);
    k_transpose_w<<<g1, 256, 0, stream>>>(Wq, Wcomb, 2048, 2048, QSCALE);
    k_transpose_w<<<g2, 256, 0, stream>>>(Wk, Wcomb + (long)2048 * 2048, 2048, 512, 1.0f);
    k_transpose_w<<<g2, 256, 0, stream>>>(Wv, Wcomb + (long)2560 * 2048, 2048, 512, 1.0f);
    k_transpose_w<<<g1, 256, 0, stream>>>(Wo, Wot, 2048, 2048, 1.0f);
  }

  // 3. fused weight products for fp32 gate/delta path
  k_wproj<<<2048, 256, 0, stream>>>(Wq, Wg, Wqg, 2048);
  k_wproj<<<2048, 256, 0, stream>>>(Wv, Wd, Wvd, 512);

  // 4. bias (fp32): pre-masked + log2e-scaled
  k_bias<<<4096, 256, 0, stream>>>(hs, Wqg, Wvd, biasb);

  // 5. fused QKV projection GEMM
  {
    dim3 gq(3072 / 128, 4096 / 128);
    k_gemm_bt<1><<<gq, 256, 0, stream>>>(hsb, Wcomb, qkv, 4096, 3072, 2048);
  }

  // 6. V transpose
  {
    dim3 gv(16, 64, 2);
    k_transpose_v<<<gv, 256, 0, stream>>>(qkv, vT);
  }

  // 7. per-(b,n) mean of V
  k_vmean2<<<1024, 256, 0, stream>>>(vT, vmean);

  // 8. flash attention with dynamic mask (1024 blocks, 64-row q tiles)
  k_attn<<<1024, 256, 0, stream>>>(qkv, biasb, vT, vmean, ob);

  // 9. output projection (fp32 out)
  {
    dim3 go(2048 / 128, 4096 / 128);
    k_gemm_bt<0><<<go, 256, 0, stream>>>(ob, Wot, out, 4096, 2048, 2048);
  }
}

// Round 6
// 344.360 us; speedup vs baseline: 1.7962x; 1.2043x over previous
//
#include <hip/hip_runtime.h>
#include <hip/hip_bf16.h>
#include <cmath>
#include <cstdint>

typedef __attribute__((ext_vector_type(8))) short short8;
typedef __attribute__((ext_vector_type(4))) float floatx4;
typedef __attribute__((ext_vector_type(4))) unsigned int uintx4;

typedef const __attribute__((address_space(1))) unsigned int* gas_p;
typedef __attribute__((address_space(3))) unsigned int* las_p;

#define LOG2E 1.4426950408889634f

__device__ inline unsigned short f2bf(float f) {
  unsigned int u = __builtin_bit_cast(unsigned int, f);
  unsigned int r = (u + 0x7FFFu + ((u >> 16) & 1u)) >> 16;
  return (unsigned short)r;
}
__device__ inline float bf2f(unsigned short h) {
  unsigned int u = ((unsigned int)h) << 16;
  return __builtin_bit_cast(float, u);
}

// ---------------- elementwise fp32 -> bf16 (float4 loads) ----------------
__global__ void k_f32_to_bf16(const float* __restrict__ in, unsigned short* __restrict__ out, int n4) {
  int i = blockIdx.x * 256 + threadIdx.x;
  if (i >= n4) return;
  float4 v = reinterpret_cast<const float4*>(in)[i];
  uint2 o;
  o.x = (unsigned)f2bf(v.x) | ((unsigned)f2bf(v.y) << 16);
  o.y = (unsigned)f2bf(v.z) | ((unsigned)f2bf(v.w) << 16);
  reinterpret_cast<uint2*>(out)[i] = o;
}

// ---------------- transpose + convert + scale: fp32 [K][N] -> bf16 [N][K] ----------------
__global__ void k_transpose_w(const float* __restrict__ in, unsigned short* __restrict__ out,
                              int K, int N, float scl) {
  __shared__ float t[32][33];
  int n0 = blockIdx.x * 32, k0 = blockIdx.y * 32;
  int tx = threadIdx.x & 31, ty = threadIdx.x >> 5; // 256 threads: ty 0..7
  #pragma unroll
  for (int r = ty; r < 32; r += 8)
    t[r][tx] = in[(long)(k0 + r) * N + n0 + tx];
  __syncthreads();
  #pragma unroll
  for (int r = ty; r < 32; r += 8)
    out[(long)(n0 + r) * K + k0 + tx] = f2bf(t[tx][r] * scl);
}

// ---------------- small fp32 GEMM: out[d][0..3] = W[d,:] @ Ws (Kw x 4) ----------------
__global__ void k_wproj(const float* __restrict__ W, const float* __restrict__ Ws,
                        float* __restrict__ out, int Kw) {
  int d = blockIdx.x;
  float a0 = 0, a1 = 0, a2 = 0, a3 = 0;
  for (int j = threadIdx.x; j < Kw; j += 256) {
    float w = W[(long)d * Kw + j];
    float4 g = reinterpret_cast<const float4*>(Ws)[j];
    a0 += w * g.x; a1 += w * g.y; a2 += w * g.z; a3 += w * g.w;
  }
  #pragma unroll
  for (int off = 1; off < 64; off <<= 1) {
    a0 += __shfl_xor(a0, off, 64); a1 += __shfl_xor(a1, off, 64);
    a2 += __shfl_xor(a2, off, 64); a3 += __shfl_xor(a3, off, 64);
  }
  __shared__ float red[4][4];
  if ((threadIdx.x & 63) == 0) {
    int wv = threadIdx.x >> 6;
    red[wv][0] = a0; red[wv][1] = a1; red[wv][2] = a2; red[wv][3] = a3;
  }
  __syncthreads();
  if (threadIdx.x < 4) {
    int nn = threadIdx.x;
    out[d * 4 + nn] = red[0][nn] + red[1][nn] + red[2][nn] + red[3][nn];
  }
}

// ---------------- bias (fp32), pre-masked + log2e-scaled ----------------
__global__ void k_bias(const float* __restrict__ hs, const float* __restrict__ Wqg,
                       const float* __restrict__ Wvd, float* __restrict__ bias) {
  int row = blockIdx.x;           // b*2048 + s
  int b = row >> 11, s = row & 2047;
  float g0 = 0, g1 = 0, g2 = 0, g3 = 0, d0 = 0, d1 = 0, d2 = 0, d3 = 0;
  const float* h = hs + (long)row * 2048;
  for (int j = threadIdx.x; j < 2048; j += 256) {
    float x = h[j];
    float4 a = reinterpret_cast<const float4*>(Wqg)[j];
    float4 c = reinterpret_cast<const float4*>(Wvd)[j];
    g0 += x * a.x; g1 += x * a.y; g2 += x * a.z; g3 += x * a.w;
    d0 += x * c.x; d1 += x * c.y; d2 += x * c.z; d3 += x * c.w;
  }
  #pragma unroll
  for (int off = 1; off < 64; off <<= 1) {
    g0 += __shfl_xor(g0, off, 64); g1 += __shfl_xor(g1, off, 64);
    g2 += __shfl_xor(g2, off, 64); g3 += __shfl_xor(g3, off, 64);
    d0 += __shfl_xor(d0, off, 64); d1 += __shfl_xor(d1, off, 64);
    d2 += __shfl_xor(d2, off, 64); d3 += __shfl_xor(d3, off, 64);
  }
  __shared__ float red[4][8];
  if ((threadIdx.x & 63) == 0) {
    int wv = threadIdx.x >> 6;
    red[wv][0] = g0; red[wv][1] = g1; red[wv][2] = g2; red[wv][3] = g3;
    red[wv][4] = d0; red[wv][5] = d1; red[wv][6] = d2; red[wv][7] = d3;
  }
  __syncthreads();
  if (threadIdx.x < 4) {
    int nn = threadIdx.x;
    float gg = red[0][nn] + red[1][nn] + red[2][nn] + red[3][nn];
    float dd = red[0][4 + nn] + red[1][4 + nn] + red[2][4 + nn] + red[3][4 + nn];
    float sig = 1.0f / (1.0f + __expf(-gg));
    float v = sig * dd;
    bias[(b * 4 + nn) * 2048 + s] = (v > 0.0f) ? v * LOG2E : -INFINITY;
  }
}

// ---------------- bf16 MFMA GEMM: C[M,N] = A[M,K] @ Bt[N,K]^T ----------------
template <int WRITE_BF16>
__global__ __launch_bounds__(256, 2) void k_gemm_bt(
    const unsigned short* __restrict__ A, const unsigned short* __restrict__ Bt,
    void* __restrict__ Cout, int M, int N, int K) {
  __shared__ __align__(16) unsigned short As[128 * 32];
  __shared__ __align__(16) unsigned short Bs[128 * 32];
  const int tid = threadIdx.x;
  const int lane = tid & 63, wave = tid >> 6;
  const int quad = lane >> 4, l16 = lane & 15;
  const long bm = (long)blockIdx.y * 128, bn = (long)blockIdx.x * 128;
  const int wm = (wave >> 1) * 64, wn = (wave & 1) * 64;

  const floatx4 fz = {0.f, 0.f, 0.f, 0.f};
  floatx4 acc[4][4];
  #pragma unroll
  for (int i = 0; i < 4; i++)
    #pragma unroll
    for (int j = 0; j < 4; j++) acc[i][j] = fz;

  const int r0 = tid >> 2, c0 = (tid & 3) * 8;
  const unsigned short* Ag = A + (bm + r0) * K + c0;
  const unsigned short* Bg = Bt + (bn + r0) * K + c0;
  unsigned short* AsW0 = As + (wave * 16) * 32;
  unsigned short* AsW1 = As + (wave * 16 + 64) * 32;
  unsigned short* BsW0 = Bs + (wave * 16) * 32;
  unsigned short* BsW1 = Bs + (wave * 16 + 64) * 32;

  for (int kt = 0; kt < K; kt += 32) {
    __syncthreads();
    __builtin_amdgcn_global_load_lds((gas_p)(const void*)(Ag + kt),
                                     (las_p)(void*)AsW0, 16, 0, 0);
    __builtin_amdgcn_global_load_lds((gas_p)(const void*)(Ag + (long)64 * K + kt),
                                     (las_p)(void*)AsW1, 16, 0, 0);
    __builtin_amdgcn_global_load_lds((gas_p)(const void*)(Bg + kt),
                                     (las_p)(void*)BsW0, 16, 0, 0);
    __builtin_amdgcn_global_load_lds((gas_p)(const void*)(Bg + (long)64 * K + kt),
                                     (las_p)(void*)BsW1, 16, 0, 0);
    __syncthreads();
    short8 af[4], bf[4];
    #pragma unroll
    for (int i = 0; i < 4; i++)
      af[i] = *reinterpret_cast<const short8*>(&As[(wm + i * 16 + l16) * 32 + quad * 8]);
    #pragma unroll
    for (int j = 0; j < 4; j++)
      bf[j] = *reinterpret_cast<const short8*>(&Bs[(wn + j * 16 + l16) * 32 + quad * 8]);
    #pragma unroll
    for (int i = 0; i < 4; i++)
      #pragma unroll
      for (int j = 0; j < 4; j++)
        acc[i][j] = __builtin_amdgcn_mfma_f32_16x16x32_bf16(af[i], bf[j], acc[i][j], 0, 0, 0);
  }
  #pragma unroll
  for (int i = 0; i < 4; i++)
    #pragma unroll
    for (int j = 0; j < 4; j++)
      #pragma unroll
      for (int r = 0; r < 4; r++) {
        const long row = bm + wm + i * 16 + quad * 4 + r;
        const long col = bn + wn + j * 16 + l16;
        const float v = acc[i][j][r];
        if (WRITE_BF16)
          ((unsigned short*)Cout)[row * N + col] = f2bf(v);
        else
          ((float*)Cout)[row * N + col] = v;
      }
}

// ---------------- bf16 transpose of V slice ----------------
__global__ void k_transpose_v(const unsigned short* __restrict__ qkv, unsigned short* __restrict__ vt) {
  __shared__ unsigned short t[32][33];
  int c0 = blockIdx.x * 32, s0 = blockIdx.y * 32, b = blockIdx.z;
  int tx = threadIdx.x & 31, ty = threadIdx.x >> 5;
  #pragma unroll
  for (int r = ty; r < 32; r += 8)
    t[r][tx] = qkv[((long)(b * 2048 + s0 + r)) * 3072 + 2560 + c0 + tx];
  __syncthreads();
  #pragma unroll
  for (int r = ty; r < 32; r += 8)
    vt[((long)(b * 512 + c0 + r)) * 2048 + s0 + tx] = t[tx][r];
}

// ---------------- vmean from vT rows (coalesced) ----------------
__global__ void k_vmean2(const unsigned short* __restrict__ vT, float* __restrict__ vmean) {
  const int row = blockIdx.x;  // 1024
  const int tid = threadIdx.x, lane = tid & 63, wave = tid >> 6;
  uintx4 v = reinterpret_cast<const uintx4*>(vT + (long)row * 2048)[tid];
  float s = 0.f;
  #pragma unroll
  for (int i = 0; i < 4; i++) {
    unsigned u = v[i];
    s += bf2f((unsigned short)(u & 0xffff)) + bf2f((unsigned short)(u >> 16));
  }
  #pragma unroll
  for (int off = 1; off < 64; off <<= 1) s += __shfl_xor(s, off, 64);
  __shared__ float red[4];
  if (lane == 0) red[wave] = s;
  __syncthreads();
  if (tid == 0) vmean[row] = (red[0] + red[1] + red[2] + red[3]) * (1.0f / 2048.0f);
}

// ---------------- flash attention with dynamic mask (transposed scores, pipelined) ----------------
// S^T = K @ Q^T, softmax in-lane over keys (R5). New in R6: register prefetch of next
// K/V/bias tile issued during current tile's compute -> global latency off the critical
// path; P gets its own LDS buffer -> 2 barriers/iter instead of 3.
// grid 1024 = qt(32, LPT) x b(2) x n(4) x g(4); 4 waves; wave owns 16 q rows.
// LDS: Ks 64x144 (18,432) + Vs 128x72 (18,432) + Ps 4x16x72 (9,216) = 46,080 B -> 3 blocks/CU.
__global__ __launch_bounds__(256, 3) void k_attn(
    const unsigned short* __restrict__ qkv,  // [4096][3072] (q | k | v); q pre-scaled by scale*log2e
    const float* __restrict__ biasb,         // [8][2048] pre-masked (-INF), log2e-scaled
    const unsigned short* __restrict__ vT,   // [1024][2048]
    const float* __restrict__ vmean,         // [1024]
    unsigned short* __restrict__ o)          // [4096][2048]
{
  int idx = blockIdx.x;
  const int g = idx & 3;
  const int n = (idx >> 2) & 3;
  const int b = (idx >> 4) & 1;
  const int qt = 31 - (idx >> 5);            // 64-row q tiles, big blocks dispatch first (LPT)
  const int tid = threadIdx.x, lane = tid & 63, wave = tid >> 6;
  const int quad = lane >> 4, l16 = lane & 15;
  const int q0 = qt * 64 + wave * 16;

  __shared__ __align__(16) unsigned short Ks[64 * 144];
  __shared__ __align__(16) unsigned short Vs[128 * 72];
  __shared__ __align__(16) unsigned short Ps[4 * 16 * 72];
  unsigned short* Psw = Ps + wave * 1152;    // 16 x 72 [q][key], per-wave private

  // Q fragments (B-operand for K@Q^T): row=q0+l16, k=ks*32+quad*8..+8
  short8 qf[4];
  {
    const unsigned short* qp = qkv + (long)(b * 2048) * 3072 + (n * 4 + g) * 128;
    #pragma unroll
    for (int ks = 0; ks < 4; ks++)
      qf[ks] = *reinterpret_cast<const short8*>(
          qp + (long)(q0 + l16) * 3072 + ks * 32 + quad * 8);
  }

  const floatx4 fz = {0.f, 0.f, 0.f, 0.f};
  floatx4 oacc[8];
  #pragma unroll
  for (int j = 0; j < 8; j++) oacc[j] = fz;
  float mrow = -INFINITY, lrow = 0.0f;       // per-lane: q = q0 + l16 (replicated across quads)

  const float* biasrow = biasb + (b * 4 + n) * 2048;
  const unsigned short* kbase = qkv + (long)(b * 2048) * 3072 + 2048 + n * 128;
  const unsigned short* vbase = vT + (long)(b * 512 + n * 128) * 2048;
  const int kk_ = tid >> 4, hdo_ = (tid & 15) * 8;   // K staging coords (row += 16/pass)
  const int hd_ = tid >> 3, ko_ = (tid & 7) * 8;     // V staging coords (row += 32/pass)

  uintx4 kreg[4], vreg[4];
  float4 breg[4];
  // prologue: load tile 0
  {
    const unsigned short* kp = kbase;
    const unsigned short* vp = vbase;
    #pragma unroll
    for (int it = 0; it < 4; it++)
      kreg[it] = *reinterpret_cast<const uintx4*>(kp + (long)(kk_ + it * 16) * 3072 + hdo_);
    #pragma unroll
    for (int it = 0; it < 4; it++)
      vreg[it] = *reinterpret_cast<const uintx4*>(vp + (long)(hd_ + it * 32) * 2048 + ko_);
    #pragma unroll
    for (int kt = 0; kt < 4; kt++)
      breg[kt] = *reinterpret_cast<const float4*>(biasrow + kt * 16 + quad * 4);
  }

  const int kend = qt * 64 + 64;
  for (int k0 = 0; k0 < kend; k0 += 64) {
    __syncthreads();  // (A) all waves done with LDS reads of previous tile
    // commit prefetched tile to LDS
    #pragma unroll
    for (int it = 0; it < 4; it++)
      *reinterpret_cast<uintx4*>(&Ks[(kk_ + it * 16) * 144 + hdo_]) = kreg[it];
    #pragma unroll
    for (int it = 0; it < 4; it++)
      *reinterpret_cast<uintx4*>(&Vs[(hd_ + it * 32) * 72 + ko_]) = vreg[it];
    float4 bcur[4];
    #pragma unroll
    for (int kt = 0; kt < 4; kt++) bcur[kt] = breg[kt];

    // issue next tile's loads (land during this tile's compute)
    if (k0 + 64 < kend) {
      const unsigned short* kp = kbase + (long)(k0 + 64) * 3072;
      const unsigned short* vp = vbase + (k0 + 64);
      #pragma unroll
      for (int it = 0; it < 4; it++)
        kreg[it] = *reinterpret_cast<const uintx4*>(kp + (long)(kk_ + it * 16) * 3072 + hdo_);
      #pragma unroll
      for (int it = 0; it < 4; it++)
        vreg[it] = *reinterpret_cast<const uintx4*>(vp + (long)(hd_ + it * 32) * 2048 + ko_);
      #pragma unroll
      for (int kt = 0; kt < 4; kt++)
        breg[kt] = *reinterpret_cast<const float4*>(biasrow + (k0 + 64) + kt * 16 + quad * 4);
    }
    __syncthreads();  // (B) staged tile visible

    const bool active = (k0 <= q0 + 15);
    if (active) {
      // S^T tile: sacc[kt] rows = keys k0+kt*16+quad*4+r, col = q0+l16. C-init = bias[key].
      floatx4 sacc[4];
      #pragma unroll
      for (int kt = 0; kt < 4; kt++)
        sacc[kt] = (floatx4){bcur[kt].x, bcur[kt].y, bcur[kt].z, bcur[kt].w};
      #pragma unroll
      for (int ks = 0; ks < 4; ks++) {
        short8 kf[4];
        #pragma unroll
        for (int kt = 0; kt < 4; kt++)
          kf[kt] = *reinterpret_cast<const short8*>(&Ks[(kt * 16 + l16) * 144 + ks * 32 + quad * 8]);
        #pragma unroll
        for (int kt = 0; kt < 4; kt++)
          sacc[kt] = __builtin_amdgcn_mfma_f32_16x16x32_bf16(kf[kt], qf[ks], sacc[kt], 0, 0, 0);
      }

      // softmax (register-only): mask, in-lane max/sum + 2 shfls
      const bool full = (k0 + 63 <= q0);
      if (!full) {
        const int diff = (q0 + l16) - (k0 + quad * 4);  // key allowed iff kt*16+r <= diff
        #pragma unroll
        for (int kt = 0; kt < 4; kt++)
          #pragma unroll
          for (int r = 0; r < 4; r++)
            if (kt * 16 + r > diff) sacc[kt][r] = -INFINITY;
      }
      float mx = -INFINITY;
      #pragma unroll
      for (int kt = 0; kt < 4; kt++)
        #pragma unroll
        for (int r = 0; r < 4; r++) mx = fmaxf(mx, sacc[kt][r]);
      mx = fmaxf(mx, __shfl_xor(mx, 16, 64));
      mx = fmaxf(mx, __shfl_xor(mx, 32, 64));
      const float mn = fmaxf(mrow, mx);
      const float mnc = fmaxf(mn, -1e38f);
      const float alpha = __builtin_amdgcn_exp2f(mrow - mnc);
      float rs = 0.0f;
      unsigned pk[4][2];
      #pragma unroll
      for (int kt = 0; kt < 4; kt++) {
        #pragma unroll
        for (int r = 0; r < 4; r++) {
          float p = __builtin_amdgcn_exp2f(sacc[kt][r] - mnc);
          sacc[kt][r] = p;
          rs += p;
        }
        #pragma unroll
        for (int r2 = 0; r2 < 2; r2++)
          pk[kt][r2] = (unsigned)f2bf(sacc[kt][2 * r2]) | ((unsigned)f2bf(sacc[kt][2 * r2 + 1]) << 16);
      }
      rs += __shfl_xor(rs, 16, 64);
      rs += __shfl_xor(rs, 32, 64);
      mrow = mn;
      lrow = lrow * alpha + rs;

      // rescale O: alpha in q=l16 space -> oacc q=quad*4+r space via bpermute
      float al[4];
      #pragma unroll
      for (int r = 0; r < 4; r++) al[r] = __shfl(alpha, quad * 4 + r, 64);
      #pragma unroll
      for (int j = 0; j < 8; j++)
        #pragma unroll
        for (int r = 0; r < 4; r++) oacc[j][r] *= al[r];

      // store packed P to Psw[q=l16][key] (own buffer, wave-private: no barrier)
      unsigned* Pd = reinterpret_cast<unsigned*>(Psw);
      #pragma unroll
      for (int kt = 0; kt < 4; kt++)
        #pragma unroll
        for (int r2 = 0; r2 < 2; r2++)
          Pd[l16 * 36 + kt * 8 + quad * 2 + r2] = pk[kt][r2];

      // O += P @ V  (A = P [q][key], B = V^T [key][hd])
      #pragma unroll
      for (int ks2 = 0; ks2 < 2; ks2++) {
        short8 pf = *reinterpret_cast<const short8*>(&Psw[l16 * 72 + ks2 * 32 + quad * 8]);
        #pragma unroll
        for (int j = 0; j < 8; j++) {
          short8 vf = *reinterpret_cast<const short8*>(&Vs[(j * 16 + l16) * 72 + ks2 * 32 + quad * 8]);
          oacc[j] = __builtin_amdgcn_mfma_f32_16x16x32_bf16(pf, vf, oacc[j], 0, 0, 0);
        }
      }
    }
  }

  // epilogue: oacc rows q=q0+quad*4+r; l lives in q=l16 space -> bpermute
  const long obase = (long)(b * 2048) * 2048 + (n * 4 + g) * 128;
  #pragma unroll
  for (int r = 0; r < 4; r++) {
    const int qrow = q0 + quad * 4 + r;
    const float l = __shfl(lrow, quad * 4 + r, 64);
    const float inv = (l > 0.0f) ? 1.0f / l : 0.0f;
    #pragma unroll
    for (int j = 0; j < 8; j++) {
      const int hd = j * 16 + l16;
      float v = oacc[j][r] * inv;
      if (l <= 0.0f) v = vmean[(b * 4 + n) * 128 + hd];  // empty row: uniform softmax over ALL keys
      o[obase + (long)qrow * 2048 + hd] = f2bf(v);
    }
  }
}

extern "C" void kernel_launch(void* const* d_in, const int* in_sizes, int n_in,
                              void* d_out, int out_size, void* d_ws, size_t ws_size,
                              hipStream_t stream) {
  const float* hs = (const float*)d_in[0];
  const float* Wq = (const float*)d_in[1];
  const float* Wk = (const float*)d_in[2];
  const float* Wv = (const float*)d_in[3];
  const float* Wg = (const float*)d_in[4];
  const float* Wd = (const float*)d_in[5];
  const float* Wo = (const float*)d_in[6];
  float* out = (float*)d_out;

  char* ws = (char*)d_ws;
  unsigned short* hsb   = (unsigned short*)(ws);               // 16,777,216 B
  unsigned short* Wcomb = (unsigned short*)(ws + 16777216);    // 12,582,912 B  [3072][2048]
  unsigned short* Wot   = (unsigned short*)(ws + 29360128);    //  8,388,608 B
  float*  Wqg   = (float*)(ws + 37748736);                     //     32,768 B
  float*  Wvd   = (float*)(ws + 37781504);                     //     32,768 B
  float*  biasb = (float*)(ws + 37814272);                     //     65,536 B
  unsigned short* qkv = (unsigned short*)(ws + 37879808);      // 25,165,824 B  [4096][3072]
  unsigned short* vT  = (unsigned short*)(ws + 63045632);      //  4,194,304 B
  float*  vmean = (float*)(ws + 67239936);                     //      4,096 B
  unsigned short* ob  = (unsigned short*)(ws + 67244032);      // 16,777,216 B

  const float QSCALE = 0.08838834764831845f * LOG2E;  // fold softmax scale + log2e into Q

  // 1. hs -> bf16
  k_f32_to_bf16<<<2097152 / 256, 256, 0, stream>>>(hs, hsb, 2097152);

  // 2. weight transposes (fp32 -> bf16, B^T layout); Wq pre-scaled
  {
    dim3 g1(2048 / 32, 2048 / 32);
    dim3 g2(512 / 32, 2048 / 32);
    k_transpose_w<<<g1, 256, 0, stream>>>(Wq, Wcomb, 2048, 2048, QSCALE);
    k_transpose_w<<<g2, 256, 0, stream>>>(Wk, Wcomb + (long)2048 * 2048, 2048, 512, 1.0f);
    k_transpose_w<<<g2, 256, 0, stream>>>(Wv, Wcomb + (long)2560 * 2048, 2048, 512, 1.0f);
    k_transpose_w<<<g1, 256, 0, stream>>>(Wo, Wot, 2048, 2048, 1.0f);
  }

  // 3. fused weight products for fp32 gate/delta path
  k_wproj<<<2048, 256, 0, stream>>>(Wq, Wg, Wqg, 2048);
  k_wproj<<<2048, 256, 0, stream>>>(Wv, Wd, Wvd, 512);

  // 4. bias (fp32): pre-masked + log2e-scaled
  k_bias<<<4096, 256, 0, stream>>>(hs, Wqg, Wvd, biasb);

  // 5. fused QKV projection GEMM
  {
    dim3 gq(3072 / 128, 4096 / 128);
    k_gemm_bt<1><<<gq, 256, 0, stream>>>(hsb, Wcomb, qkv, 4096, 3072, 2048);
  }

  // 6. V transpose
  {
    dim3 gv(16, 64, 2);
    k_transpose_v<<<gv, 256, 0, stream>>>(qkv, vT);
  }

  // 7. per-(b,n) mean of V
  k_vmean2<<<1024, 256, 0, stream>>>(vT, vmean);

  // 8. flash attention with dynamic mask (pipelined, 2 barriers/iter)
  k_attn<<<1024, 256, 0, stream>>>(qkv, biasb, vT, vmean, ob);

  // 9. output projection (fp32 out)
  {
    dim3 go(2048 / 128, 4096 / 128);
    k_gemm_bt<0><<<go, 256, 0, stream>>>(ob, Wot, out, 4096, 2048, 2048);
  }
}